// Round 1
// baseline (520.352 us; speedup 1.0000x reference)
//
#include <hip/hip_runtime.h>
#include <math.h>

#define NN 100000
#define NE 3200000
#define INC 128
#define HID 16
#define OC 40

__global__ void k_zero_i(int* __restrict__ p, int n) {
    int i = blockIdx.x * blockDim.x + threadIdx.x;
    if (i < n) p[i] = 0;
}

// deg[d] = #in-edges (self-loop added later as +1 in k_dis)
__global__ void k_deg(const int* __restrict__ dst, int* __restrict__ deg) {
    int e = blockIdx.x * blockDim.x + threadIdx.x;
    if (e < NE) {
        unsigned d = (unsigned)dst[e];
        if (d < NN) atomicAdd(&deg[d], 1);
    }
}

__global__ void k_dis(const int* __restrict__ deg, float* __restrict__ dis) {
    int i = blockIdx.x * blockDim.x + threadIdx.x;
    if (i < NN) dis[i] = rsqrtf((float)(deg[i] + 1));  // +1 = self-loop
}

// h1 = x @ W1 : [NN,128] @ [128,16] -> [NN,16]
// 256 threads = 16 rows x 16 cols per block; x tile + W1 staged in LDS.
__global__ __launch_bounds__(256) void k_gemm1(const float* __restrict__ x,
                                               const float* __restrict__ W1,
                                               float* __restrict__ h1) {
    __shared__ float xs[16][INC + 1];  // +1 pad: kills stride-128 bank conflict
    __shared__ float ws[INC][HID];
    int t = threadIdx.x;
    int rowbase = blockIdx.x * 16;  // NN/16 = 6250 exact
#pragma unroll
    for (int i = 0; i < 8; ++i) {
        int idx = t + i * 256;
        xs[idx >> 7][idx & 127] = x[(long long)(rowbase) * INC + idx];
    }
#pragma unroll
    for (int i = 0; i < 8; ++i) {
        int idx = t + i * 256;
        ws[idx >> 4][idx & 15] = W1[idx];
    }
    __syncthreads();
    int r = t >> 4, c = t & 15;
    float acc = 0.f;
#pragma unroll
    for (int k = 0; k < INC; ++k) acc += xs[r][k] * ws[k][c];
    h1[(rowbase + r) * HID + c] = acc;
}

// agg[i][c] = dis[i]^2 * hin[i][c]   (self-loop contribution, non-atomic init)
__global__ void k_init_self(const float* __restrict__ hin, const float* __restrict__ dis,
                            float* __restrict__ agg) {
    int idx = blockIdx.x * blockDim.x + threadIdx.x;
    if (idx < NN * HID) {
        int i = idx >> 4;
        float d = dis[i];
        agg[idx] = d * d * hin[idx];
    }
}

// agg[dst][c] += dis[src]*dis[dst] * hin[src][c]; 16 threads per edge
__global__ void k_scatter(const int* __restrict__ src, const int* __restrict__ dst,
                          const float* __restrict__ dis, const float* __restrict__ hin,
                          float* __restrict__ agg) {
    long long tid = (long long)blockIdx.x * blockDim.x + threadIdx.x;
    if (tid >= (long long)NE * HID) return;
    int e = (int)(tid >> 4), c = (int)(tid & 15);
    unsigned s = (unsigned)src[e], d = (unsigned)dst[e];
    if (s >= NN || d >= NN) return;  // defensive: dtype surprise -> clean fail, not fault
    float nrm = dis[s] * dis[d];
    atomicAdd(&agg[d * HID + c], nrm * hin[s * HID + c]);
}

// h = relu(agg1 + b1) in place; agg2 init = dis^2 * h (layer-2 self-loop)
__global__ void k_relu_init2(float* __restrict__ agg1, const float* __restrict__ b1,
                             const float* __restrict__ dis, float* __restrict__ agg2) {
    int idx = blockIdx.x * blockDim.x + threadIdx.x;
    if (idx < NN * HID) {
        int i = idx >> 4, c = idx & 15;
        float v = fmaxf(agg1[idx] + b1[c], 0.f);
        agg1[idx] = v;
        float d = dis[i];
        agg2[idx] = d * d * v;
    }
}

// out[i] = log_softmax(agg2[i] @ W2 + b2); one row per thread, W2/b2 in LDS
__global__ __launch_bounds__(256) void k_final(const float* __restrict__ agg2,
                                               const float* __restrict__ W2,
                                               const float* __restrict__ b2,
                                               float* __restrict__ out) {
    __shared__ float w2s[HID * OC];
    __shared__ float b2s[OC];
    int t = threadIdx.x;
    for (int i = t; i < HID * OC; i += 256) w2s[i] = W2[i];
    if (t < OC) b2s[t] = b2[t];
    __syncthreads();
    int row = blockIdx.x * 256 + t;
    if (row >= NN) return;
    float a[HID];
#pragma unroll
    for (int k = 0; k < HID; ++k) a[k] = agg2[row * HID + k];
    float z[OC];
#pragma unroll
    for (int c = 0; c < OC; ++c) z[c] = b2s[c];
#pragma unroll
    for (int k = 0; k < HID; ++k) {
        float av = a[k];
#pragma unroll
        for (int c = 0; c < OC; ++c) z[c] += av * w2s[k * OC + c];
    }
    float m = z[0];
#pragma unroll
    for (int c = 1; c < OC; ++c) m = fmaxf(m, z[c]);
    float ssum = 0.f;
#pragma unroll
    for (int c = 0; c < OC; ++c) ssum += expf(z[c] - m);
    float lse = m + logf(ssum);
#pragma unroll
    for (int c = 0; c < OC; ++c) out[row * OC + c] = z[c] - lse;
}

extern "C" void kernel_launch(void* const* d_in, const int* in_sizes, int n_in,
                              void* d_out, int out_size, void* d_ws, size_t ws_size,
                              hipStream_t stream) {
    const float* x  = (const float*)d_in[0];
    const int*   ei = (const int*)d_in[1];
    const float* W1 = (const float*)d_in[2];
    const float* b1 = (const float*)d_in[3];
    const float* W2 = (const float*)d_in[4];
    const float* b2 = (const float*)d_in[5];
    float* out = (float*)d_out;

    const int* src = ei;        // edge_index[0]
    const int* dst = ei + NE;   // edge_index[1]

    char* ws = (char*)d_ws;
    int*   deg  = (int*)ws;                      // NN ints
    float* dis  = (float*)(ws + (size_t)NN * 4); // NN floats
    float* bufA = (float*)(ws + (size_t)NN * 8); // NN*HID: h1, later agg2
    float* bufB = bufA + (size_t)NN * HID;       // NN*HID: agg1, later h
    // total ws: 0.8MB + 12.8MB = 13.6MB

    dim3 B(256);
    int gN   = (NN + 255) / 256;
    int gE   = (NE + 255) / 256;
    int gNH  = (NN * HID + 255) / 256;
    int gEH  = (int)(((long long)NE * HID + 255) / 256);

    k_zero_i<<<gN, B, 0, stream>>>(deg, NN);
    k_deg<<<gE, B, 0, stream>>>(dst, deg);
    k_dis<<<gN, B, 0, stream>>>(deg, dis);
    k_gemm1<<<NN / 16, B, 0, stream>>>(x, W1, bufA);
    k_init_self<<<gNH, B, 0, stream>>>(bufA, dis, bufB);
    k_scatter<<<gEH, B, 0, stream>>>(src, dst, dis, bufA, bufB);
    k_relu_init2<<<gNH, B, 0, stream>>>(bufB, b1, dis, bufA);
    k_scatter<<<gEH, B, 0, stream>>>(src, dst, dis, bufB, bufA);
    k_final<<<gN, B, 0, stream>>>(bufA, W2, b2, out);
}